// Round 1
// baseline (10.103 us; speedup 1.0000x reference)
//
#include <hip/hip_runtime.h>

// out(x) per branch k:  sum_h w_k2[h] * relu(w_k1[h]*x + b_k1[h]) + b_k2
// If b_k1 == 0 (true for the harness inputs), this is piecewise-linear with a
// single breakpoint at 0:  out = x * s_pos (x>0) or x * s_neg (x<0), + b_k2,
// where s_pos = sum_{w1[h]>0} w1[h]*w2[h], s_neg = sum_{w1[h]<0} w1[h]*w2[h].
// We compute the slopes per block (cheap, weights are L2-resident) and keep a
// fully general fallback path guarded by a uniform flag (any b1 != 0).

__global__ __launch_bounds__(256) void PredEnvHatYSep_kernel(
    const int*   __restrict__ g,
    const float* __restrict__ x,
    const float* __restrict__ w11, const float* __restrict__ b11,
    const float* __restrict__ w12, const float* __restrict__ b12,
    const float* __restrict__ w21, const float* __restrict__ b21,
    const float* __restrict__ w22, const float* __restrict__ b22,
    float* __restrict__ out, int n)
{
    __shared__ float sh_pos[4], sh_neg[4];
    __shared__ int   sh_bad[4];

    const int tid = threadIdx.x;

    // ---- Phase 1: per-block slope reduction (threads 0..127 -> branch 1,
    //               threads 128..255 -> branch 2; H == 128) ----
    {
        const int  h   = tid & 127;
        const bool br1 = tid < 128;
        const float* w1 = br1 ? w11 : w21;
        const float* w2 = br1 ? w12 : w22;
        const float* b1 = br1 ? b11 : b21;

        const float a = w1[h];
        const float p = a * w2[h];
        float pos = (a > 0.0f) ? p : 0.0f;
        float neg = (a < 0.0f) ? p : 0.0f;
        int   bad = (b1[h] != 0.0f) ? 1 : 0;

        #pragma unroll
        for (int off = 32; off; off >>= 1) {
            pos += __shfl_down(pos, off);
            neg += __shfl_down(neg, off);
            bad += __shfl_down(bad, off);
        }
        if ((tid & 63) == 0) {
            const int w = tid >> 6;
            sh_pos[w] = pos;
            sh_neg[w] = neg;
            sh_bad[w] = bad;
        }
    }
    __syncthreads();

    const float spos1 = sh_pos[0] + sh_pos[1];
    const float sneg1 = sh_neg[0] + sh_neg[1];
    const float spos2 = sh_pos[2] + sh_pos[3];
    const float sneg2 = sh_neg[2] + sh_neg[3];
    const int   nbad  = sh_bad[0] + sh_bad[1] + sh_bad[2] + sh_bad[3];
    const float c1 = b12[0];
    const float c2 = b22[0];

    // ---- Phase 2: elementwise, 4 elements/thread, vectorized ----
    const int idx  = blockIdx.x * 256 + tid;   // float4 group index
    const int base = idx * 4;
    if (base >= n) return;

    if (base + 3 < n) {
        const int4   gv = reinterpret_cast<const int4*>(g)[idx];
        const float4 xv = reinterpret_cast<const float4*>(x)[idx];
        float4 ov;

        if (nbad == 0) {
            auto f = [&](int gi, float xi) -> float {
                const float o1 = xi * (xi > 0.0f ? spos1 : sneg1) + c1;
                const float o2 = xi * (xi > 0.0f ? spos2 : sneg2) + c2;
                return gi == 0 ? o1 : (gi == 1 ? o2 : 0.0f);
            };
            ov.x = f(gv.x, xv.x); ov.y = f(gv.y, xv.y);
            ov.z = f(gv.z, xv.z); ov.w = f(gv.w, xv.w);
        } else {
            auto f = [&](int gi, float xi) -> float {
                float acc1 = 0.0f, acc2 = 0.0f;
                for (int h = 0; h < 128; ++h) {
                    acc1 += w12[h] * fmaxf(xi * w11[h] + b11[h], 0.0f);
                    acc2 += w22[h] * fmaxf(xi * w21[h] + b21[h], 0.0f);
                }
                return gi == 0 ? acc1 + c1 : (gi == 1 ? acc2 + c2 : 0.0f);
            };
            ov.x = f(gv.x, xv.x); ov.y = f(gv.y, xv.y);
            ov.z = f(gv.z, xv.z); ov.w = f(gv.w, xv.w);
        }
        reinterpret_cast<float4*>(out)[idx] = ov;
    } else {
        // scalar tail (not taken for N = 2^21, kept for generality)
        for (int i = base; i < n; ++i) {
            const int   gi = g[i];
            const float xi = x[i];
            float o;
            if (nbad == 0) {
                const float o1 = xi * (xi > 0.0f ? spos1 : sneg1) + c1;
                const float o2 = xi * (xi > 0.0f ? spos2 : sneg2) + c2;
                o = gi == 0 ? o1 : (gi == 1 ? o2 : 0.0f);
            } else {
                float acc1 = 0.0f, acc2 = 0.0f;
                for (int h = 0; h < 128; ++h) {
                    acc1 += w12[h] * fmaxf(xi * w11[h] + b11[h], 0.0f);
                    acc2 += w22[h] * fmaxf(xi * w21[h] + b21[h], 0.0f);
                }
                o = gi == 0 ? acc1 + c1 : (gi == 1 ? acc2 + c2 : 0.0f);
            }
            out[i] = o;
        }
    }
}

extern "C" void kernel_launch(void* const* d_in, const int* in_sizes, int n_in,
                              void* d_out, int out_size, void* d_ws, size_t ws_size,
                              hipStream_t stream) {
    const int*   g   = (const int*)  d_in[0];
    const float* x   = (const float*)d_in[1];
    const float* w11 = (const float*)d_in[2];
    const float* b11 = (const float*)d_in[3];
    const float* w12 = (const float*)d_in[4];
    const float* b12 = (const float*)d_in[5];
    const float* w21 = (const float*)d_in[6];
    const float* b21 = (const float*)d_in[7];
    const float* w22 = (const float*)d_in[8];
    const float* b22 = (const float*)d_in[9];
    float* out = (float*)d_out;

    const int n = in_sizes[1];                 // N elements
    const int blocks = (n + 1023) / 1024;      // 4 elems/thread, 256 threads

    PredEnvHatYSep_kernel<<<blocks, 256, 0, stream>>>(
        g, x, w11, b11, w12, b12, w21, b21, w22, b22, out, n);
}